// Round 1
// baseline (1564.741 us; speedup 1.0000x reference)
//
#include <hip/hip_runtime.h>
#include <hip/hip_bf16.h>
#include <cstdint>
#include <cstddef>

#define BTOK  8192
#define DIM   1024
#define NEXP  8
#define NHID  4096
#define HHALF 2048

typedef __bf16 bf16x8 __attribute__((ext_vector_type(8)));
typedef float  floatx4 __attribute__((ext_vector_type(4)));

// ---- workspace layout (bytes) ----
#define O_COUNTS 0
#define O_BASE   256
#define O_TOKB   1024
#define O_TOKW   (O_TOKB + (size_t)NEXP*BTOK*4)                // 263168
#define O_ZBF    (O_TOKW + (size_t)NEXP*BTOK*4)                // 525312
#define O_W1T    (O_ZBF + (size_t)BTOK*DIM*2)                  // +16.78MB
#define O_W2T    (O_W1T + (size_t)NEXP*DIM*NHID*2)             // +67MB
#define O_HBUF   (O_W2T + (size_t)NEXP*DIM*NHID*2)             // +67MB
#define WS_NEED  (O_HBUF + (size_t)2*BTOK*HHALF*2)             // +67MB = ~218.6MB

// ---------------- init: zero out + counters ----------------
__global__ void k_init(float* __restrict__ out, int* __restrict__ counts) {
  int i = blockIdx.x * blockDim.x + threadIdx.x;
  if (i < NEXP) counts[i] = 0;
  float4 z4 = {0.f, 0.f, 0.f, 0.f};
  float4* o = (float4*)out;
  int n = BTOK * DIM / 4;
  for (int j = i; j < n; j += gridDim.x * blockDim.x) o[j] = z4;
}

// ---------------- transpose fp32 [Z][R][C] -> bf16 [Z][C][R] ----------------
__global__ __launch_bounds__(256) void k_transpose(
    const float* __restrict__ src, __hip_bfloat16* __restrict__ dst, int R, int C) {
  __shared__ float tile[32][33];
  int zz = blockIdx.z;
  const float* s = src + (size_t)zz * R * C;
  __hip_bfloat16* d = dst + (size_t)zz * R * C;
  int c0 = blockIdx.x * 32, r0 = blockIdx.y * 32;
  int tx = threadIdx.x & 31, ty = threadIdx.x >> 5;
#pragma unroll
  for (int i = ty; i < 32; i += 8)
    tile[i][tx] = s[(size_t)(r0 + i) * C + c0 + tx];
  __syncthreads();
#pragma unroll
  for (int i = ty; i < 32; i += 8)
    d[(size_t)(c0 + i) * R + r0 + tx] = __float2bfloat16(tile[tx][i]);
}

// ---------------- gating: logits, softmax, top-2, routing lists, z->bf16 ----------------
__global__ __launch_bounds__(256) void k_gate(
    const float* __restrict__ z, const float* __restrict__ Wg,
    const float* __restrict__ bg, int* __restrict__ counts,
    int* __restrict__ tokb, float* __restrict__ tokw,
    __hip_bfloat16* __restrict__ zbf) {
  __shared__ float wgT[NEXP * DIM];  // transposed: [e][d], conflict-free reads
  int tid = threadIdx.x;
  for (int i = tid; i < NEXP * DIM; i += 256) {
    int d = i >> 3, e = i & 7;
    wgT[e * DIM + d] = Wg[i];
  }
  __syncthreads();
  int lane = tid & 63;
  int b = blockIdx.x * 4 + (tid >> 6);   // one wave per token
  const float* zr = z + (size_t)b * DIM;
  float zv[16];
#pragma unroll
  for (int i = 0; i < 16; i++) zv[i] = zr[lane + 64 * i];
  __hip_bfloat16* zb = zbf + (size_t)b * DIM;
#pragma unroll
  for (int i = 0; i < 16; i++) zb[lane + 64 * i] = __float2bfloat16(zv[i]);
  float acc[NEXP];
#pragma unroll
  for (int e = 0; e < NEXP; e++) {
    float a = 0.f;
#pragma unroll
    for (int i = 0; i < 16; i++) a += zv[i] * wgT[e * DIM + lane + 64 * i];
    acc[e] = a;
  }
#pragma unroll
  for (int off = 32; off > 0; off >>= 1) {
#pragma unroll
    for (int e = 0; e < NEXP; e++) acc[e] += __shfl_down(acc[e], off);
  }
  if (lane == 0) {
    float mx = -1e30f;
#pragma unroll
    for (int e = 0; e < NEXP; e++) { acc[e] += bg[e]; mx = fmaxf(mx, acc[e]); }
    float s = 0.f;
#pragma unroll
    for (int e = 0; e < NEXP; e++) { acc[e] = expf(acc[e] - mx); s += acc[e]; }
    float inv = 1.f / s;
    int i1 = -1, i2 = -1; float v1 = -1.f, v2 = -1.f;
#pragma unroll
    for (int e = 0; e < NEXP; e++) {   // stable (first index wins ties) like lax.top_k
      float w = acc[e] * inv;
      if (w > v1) { v2 = v1; i2 = i1; v1 = w; i1 = e; }
      else if (w > v2) { v2 = w; i2 = e; }
    }
    int p1 = atomicAdd(&counts[i1], 1);
    tokb[i1 * BTOK + p1] = b; tokw[i1 * BTOK + p1] = v1;
    int p2 = atomicAdd(&counts[i2], 1);
    tokb[i2 * BTOK + p2] = b; tokw[i2 * BTOK + p2] = v2;
  }
}

// ---------------- prefix sum of counts ----------------
__global__ void k_base(const int* __restrict__ counts, int* __restrict__ base) {
  if (threadIdx.x == 0 && blockIdx.x == 0) {
    int s = 0;
    for (int e = 0; e < NEXP; e++) { base[e] = s; s += counts[e]; }
  }
}

// ---------------- GEMM1: h[slot, n] = relu(zbf[tok]·W1T[e] + b1), n in one H-half ----------------
__global__ __launch_bounds__(256) void k_gemm1(
    const __hip_bfloat16* __restrict__ zbf, const __hip_bfloat16* __restrict__ w1t,
    const float* __restrict__ b1, const int* __restrict__ counts,
    const int* __restrict__ base, const int* __restrict__ tokb,
    __hip_bfloat16* __restrict__ hbuf, int hbase) {
  int e = blockIdx.z;
  int cnt = counts[e];
  int m0 = blockIdx.x * 128;
  if (m0 >= cnt) return;
  int n0 = blockIdx.y * 128;
  int gb = base[e];

  __shared__ __align__(16) __hip_bfloat16 lA[128 * 72];  // row stride 72 (=144B, 2-way free)
  __shared__ __align__(16) __hip_bfloat16 lB[128 * 72];
  __shared__ int ltok[128];

  int tid = threadIdx.x;
  if (tid < 128) {
    int m = m0 + tid; if (m >= cnt) m = cnt - 1;
    ltok[tid] = tokb[e * BTOK + m];
  }
  __syncthreads();

  int lane = tid & 63;
  int wv = tid >> 6;
  int wmoff = (wv >> 1) * 64;
  int wnoff = (wv & 1) * 64;
  int lrow = lane & 15;
  int quad = lane >> 4;
  int rs = tid >> 3, cs = tid & 7;   // staging: row, 16B-chunk

  floatx4 acc[4][4];
#pragma unroll
  for (int i = 0; i < 4; i++)
#pragma unroll
    for (int j = 0; j < 4; j++) { floatx4 zf = {0.f,0.f,0.f,0.f}; acc[i][j] = zf; }

  const ushort* zb = (const ushort*)zbf;
  const ushort* w1 = (const ushort*)w1t;
  ushort* sA = (ushort*)lA;
  ushort* sB = (ushort*)lB;

  for (int k0 = 0; k0 < DIM; k0 += 64) {
#pragma unroll
    for (int i = 0; i < 4; i++) {
      int r = rs + 32 * i;
      uint4 va = *(const uint4*)(zb + (size_t)ltok[r] * DIM + k0 + cs * 8);
      *(uint4*)(sA + r * 72 + cs * 8) = va;
      uint4 vb = *(const uint4*)(w1 + (size_t)(e * NHID + hbase + n0 + r) * DIM + k0 + cs * 8);
      *(uint4*)(sB + r * 72 + cs * 8) = vb;
    }
    __syncthreads();
#pragma unroll
    for (int kk = 0; kk < 2; kk++) {
      bf16x8 af[4], bfr[4];
#pragma unroll
      for (int i = 0; i < 4; i++) {
        uint4 t = *(const uint4*)(sA + (wmoff + i * 16 + lrow) * 72 + kk * 32 + quad * 8);
        af[i] = __builtin_bit_cast(bf16x8, t);
      }
#pragma unroll
      for (int j = 0; j < 4; j++) {
        uint4 t = *(const uint4*)(sB + (wnoff + j * 16 + lrow) * 72 + kk * 32 + quad * 8);
        bfr[j] = __builtin_bit_cast(bf16x8, t);
      }
#pragma unroll
      for (int i = 0; i < 4; i++)
#pragma unroll
        for (int j = 0; j < 4; j++)
          acc[i][j] = __builtin_amdgcn_mfma_f32_16x16x32_bf16(af[i], bfr[j], acc[i][j], 0, 0, 0);
    }
    __syncthreads();
  }

#pragma unroll
  for (int i = 0; i < 4; i++) {
    int mloc = wmoff + i * 16 + quad * 4;
#pragma unroll
    for (int r = 0; r < 4; r++) {
      int m = m0 + mloc + r;
      if (m < cnt) {
#pragma unroll
        for (int j = 0; j < 4; j++) {
          int n = n0 + wnoff + j * 16 + lrow;
          float v = acc[i][j][r] + b1[e * NHID + hbase + n];
          v = fmaxf(v, 0.f);
          hbuf[(size_t)(gb + m) * HHALF + n] = __float2bfloat16(v);
        }
      }
    }
  }
}

// ---------------- GEMM2: out[tok] += w * (h·W2T[e] + b2), K over one H-half ----------------
__global__ __launch_bounds__(256) void k_gemm2(
    const __hip_bfloat16* __restrict__ hbuf, const __hip_bfloat16* __restrict__ w2t,
    const float* __restrict__ b2, const int* __restrict__ counts,
    const int* __restrict__ base, const int* __restrict__ tokb,
    const float* __restrict__ tokw, float* __restrict__ out, int hbase) {
  int e = blockIdx.z;
  int cnt = counts[e];
  int m0 = blockIdx.x * 128;
  if (m0 >= cnt) return;
  int n0 = blockIdx.y * 128;
  int gb = base[e];

  __shared__ __align__(16) __hip_bfloat16 lA[128 * 72];
  __shared__ __align__(16) __hip_bfloat16 lB[128 * 72];
  __shared__ int ltok[128];
  __shared__ float ltw[128];

  int tid = threadIdx.x;
  if (tid < 128) {
    int m = m0 + tid; if (m >= cnt) m = cnt - 1;
    ltok[tid] = tokb[e * BTOK + m];
    ltw[tid]  = tokw[e * BTOK + m];
  }
  __syncthreads();

  int lane = tid & 63;
  int wv = tid >> 6;
  int wmoff = (wv >> 1) * 64;
  int wnoff = (wv & 1) * 64;
  int lrow = lane & 15;
  int quad = lane >> 4;
  int rs = tid >> 3, cs = tid & 7;

  floatx4 acc[4][4];
#pragma unroll
  for (int i = 0; i < 4; i++)
#pragma unroll
    for (int j = 0; j < 4; j++) { floatx4 zf = {0.f,0.f,0.f,0.f}; acc[i][j] = zf; }

  const ushort* hb = (const ushort*)hbuf;
  const ushort* w2 = (const ushort*)w2t;
  ushort* sA = (ushort*)lA;
  ushort* sB = (ushort*)lB;

  for (int k0 = 0; k0 < HHALF; k0 += 64) {
#pragma unroll
    for (int i = 0; i < 4; i++) {
      int r = rs + 32 * i;
      int mm = m0 + r; if (mm >= cnt) mm = cnt - 1;
      uint4 va = *(const uint4*)(hb + (size_t)(gb + mm) * HHALF + k0 + cs * 8);
      *(uint4*)(sA + r * 72 + cs * 8) = va;
      uint4 vb = *(const uint4*)(w2 + (size_t)(e * DIM + n0 + r) * NHID + hbase + k0 + cs * 8);
      *(uint4*)(sB + r * 72 + cs * 8) = vb;
    }
    __syncthreads();
#pragma unroll
    for (int kk = 0; kk < 2; kk++) {
      bf16x8 af[4], bfr[4];
#pragma unroll
      for (int i = 0; i < 4; i++) {
        uint4 t = *(const uint4*)(sA + (wmoff + i * 16 + lrow) * 72 + kk * 32 + quad * 8);
        af[i] = __builtin_bit_cast(bf16x8, t);
      }
#pragma unroll
      for (int j = 0; j < 4; j++) {
        uint4 t = *(const uint4*)(sB + (wnoff + j * 16 + lrow) * 72 + kk * 32 + quad * 8);
        bfr[j] = __builtin_bit_cast(bf16x8, t);
      }
#pragma unroll
      for (int i = 0; i < 4; i++)
#pragma unroll
        for (int j = 0; j < 4; j++)
          acc[i][j] = __builtin_amdgcn_mfma_f32_16x16x32_bf16(af[i], bfr[j], acc[i][j], 0, 0, 0);
    }
    __syncthreads();
  }

#pragma unroll
  for (int i = 0; i < 4; i++) {
    int mloc = wmoff + i * 16 + quad * 4;
#pragma unroll
    for (int r = 0; r < 4; r++) {
      int m = m0 + mloc + r;
      if (m < cnt) {
        int t  = ltok[mloc + r];
        float w = ltw[mloc + r];
#pragma unroll
        for (int j = 0; j < 4; j++) {
          int n = n0 + wnoff + j * 16 + lrow;
          float v = acc[i][j][r] + b2[e * DIM + n];
          atomicAdd(&out[(size_t)t * DIM + n], w * v);
        }
      }
    }
  }
}

extern "C" void kernel_launch(void* const* d_in, const int* in_sizes, int n_in,
                              void* d_out, int out_size, void* d_ws, size_t ws_size,
                              hipStream_t stream) {
  const float* z  = (const float*)d_in[0];
  const float* Wg = (const float*)d_in[1];
  const float* bg = (const float*)d_in[2];
  const float* W1 = (const float*)d_in[3];
  const float* b1 = (const float*)d_in[4];
  const float* W2 = (const float*)d_in[5];
  const float* b2 = (const float*)d_in[6];
  float* out = (float*)d_out;
  char* ws = (char*)d_ws;
  if (ws_size < WS_NEED) return;  // workspace too small; bench will flag

  int*   counts = (int*)(ws + O_COUNTS);
  int*   base   = (int*)(ws + O_BASE);
  int*   tokb   = (int*)(ws + O_TOKB);
  float* tokw   = (float*)(ws + O_TOKW);
  __hip_bfloat16* zbf  = (__hip_bfloat16*)(ws + O_ZBF);
  __hip_bfloat16* w1t  = (__hip_bfloat16*)(ws + O_W1T);
  __hip_bfloat16* w2t  = (__hip_bfloat16*)(ws + O_W2T);
  __hip_bfloat16* hbuf = (__hip_bfloat16*)(ws + O_HBUF);

  k_init<<<512, 256, 0, stream>>>(out, counts);
  // W1 [E][D][H] -> w1t [E][H][D] ; W2 [E][H][D] -> w2t [E][D][H]
  k_transpose<<<dim3(NHID / 32, DIM / 32, NEXP), 256, 0, stream>>>(W1, w1t, DIM, NHID);
  k_transpose<<<dim3(DIM / 32, NHID / 32, NEXP), 256, 0, stream>>>(W2, w2t, NHID, DIM);
  k_gate<<<BTOK / 4, 256, 0, stream>>>(z, Wg, bg, counts, tokb, tokw, zbf);
  k_base<<<1, 64, 0, stream>>>(counts, base);
  for (int half = 0; half < 2; half++) {
    k_gemm1<<<dim3(BTOK / 128, HHALF / 128, NEXP), 256, 0, stream>>>(
        zbf, w1t, b1, counts, base, tokb, hbuf, half * HHALF);
    k_gemm2<<<dim3(BTOK / 128, DIM / 128, NEXP), 256, 0, stream>>>(
        hbuf, w2t, b2, counts, base, tokb, tokw, out, half * HHALF);
  }
}

// Round 2
// 1407.713 us; speedup vs baseline: 1.1115x; 1.1115x over previous
//
#include <hip/hip_runtime.h>
#include <hip/hip_bf16.h>
#include <cstdint>
#include <cstddef>

#define BTOK  8192
#define DIM   1024
#define NEXP  8
#define NHID  4096
#define HHALF 2048

typedef __bf16 bf16x8 __attribute__((ext_vector_type(8)));
typedef float  floatx4 __attribute__((ext_vector_type(4)));

// ---- workspace layout (bytes) ----
#define O_COUNTS 0
#define O_BASE   256
#define O_TOKB   1024
#define O_TOKW   (O_TOKB + (size_t)NEXP*BTOK*4)
#define O_CE     (O_TOKW + (size_t)NEXP*BTOK*4)
#define O_CP     (O_CE + (size_t)2*BTOK*4)
#define O_CW     (O_CP + (size_t)2*BTOK*4)
#define O_ZBF    (O_CW + (size_t)2*BTOK*4)
#define O_W1T    (O_ZBF + (size_t)BTOK*DIM*2)
#define O_W2T    (O_W1T + (size_t)NEXP*DIM*NHID*2)
#define O_HBUF   (O_W2T + (size_t)NEXP*DIM*NHID*2)
#define WS_BASE  (O_HBUF + (size_t)2*BTOK*HHALF*2)     // ~218.8 MB (atomic fallback)
#define O_YBUF   WS_BASE
#define WS_FULL  (O_YBUF + (size_t)2*BTOK*DIM*4)       // ~286 MB (ybuf path)

__device__ __forceinline__ void gload_lds16(const void* g, void* l) {
  __builtin_amdgcn_global_load_lds(
      (const __attribute__((address_space(1))) void*)g,
      (__attribute__((address_space(3))) void*)l, 16, 0, 0);
}

// ---------------- init: zero out + counters ----------------
__global__ void k_init(float* __restrict__ out, int* __restrict__ counts) {
  int i = blockIdx.x * blockDim.x + threadIdx.x;
  if (i < NEXP) counts[i] = 0;
  float4 z4 = {0.f, 0.f, 0.f, 0.f};
  float4* o = (float4*)out;
  int n = BTOK * DIM / 4;
  for (int j = i; j < n; j += gridDim.x * blockDim.x) o[j] = z4;
}

// ---------------- transpose fp32 [Z][R][C] -> bf16 [Z][C][R] ----------------
__global__ __launch_bounds__(256) void k_transpose(
    const float* __restrict__ src, __hip_bfloat16* __restrict__ dst, int R, int C) {
  __shared__ float tile[32][33];
  int zz = blockIdx.z;
  const float* s = src + (size_t)zz * R * C;
  __hip_bfloat16* d = dst + (size_t)zz * R * C;
  int c0 = blockIdx.x * 32, r0 = blockIdx.y * 32;
  int tx = threadIdx.x & 31, ty = threadIdx.x >> 5;
#pragma unroll
  for (int i = ty; i < 32; i += 8)
    tile[i][tx] = s[(size_t)(r0 + i) * C + c0 + tx];
  __syncthreads();
#pragma unroll
  for (int i = ty; i < 32; i += 8)
    d[(size_t)(c0 + i) * R + r0 + tx] = __float2bfloat16(tile[tx][i]);
}

// ---------------- gating ----------------
__global__ __launch_bounds__(256) void k_gate(
    const float* __restrict__ z, const float* __restrict__ Wg,
    const float* __restrict__ bg, int* __restrict__ counts,
    int* __restrict__ tokb, float* __restrict__ tokw,
    int* __restrict__ ce, int* __restrict__ cp, float* __restrict__ cw,
    __hip_bfloat16* __restrict__ zbf) {
  __shared__ float wgT[NEXP * DIM];
  int tid = threadIdx.x;
  for (int i = tid; i < NEXP * DIM; i += 256) {
    int d = i >> 3, e = i & 7;
    wgT[e * DIM + d] = Wg[i];
  }
  __syncthreads();
  int lane = tid & 63;
  int b = blockIdx.x * 4 + (tid >> 6);
  const float* zr = z + (size_t)b * DIM;
  float zv[16];
#pragma unroll
  for (int i = 0; i < 16; i++) zv[i] = zr[lane + 64 * i];
  __hip_bfloat16* zb = zbf + (size_t)b * DIM;
#pragma unroll
  for (int i = 0; i < 16; i++) zb[lane + 64 * i] = __float2bfloat16(zv[i]);
  float acc[NEXP];
#pragma unroll
  for (int e = 0; e < NEXP; e++) {
    float a = 0.f;
#pragma unroll
    for (int i = 0; i < 16; i++) a += zv[i] * wgT[e * DIM + lane + 64 * i];
    acc[e] = a;
  }
#pragma unroll
  for (int off = 32; off > 0; off >>= 1) {
#pragma unroll
    for (int e = 0; e < NEXP; e++) acc[e] += __shfl_down(acc[e], off);
  }
  if (lane == 0) {
    float mx = -1e30f;
#pragma unroll
    for (int e = 0; e < NEXP; e++) { acc[e] += bg[e]; mx = fmaxf(mx, acc[e]); }
    float s = 0.f;
#pragma unroll
    for (int e = 0; e < NEXP; e++) { acc[e] = expf(acc[e] - mx); s += acc[e]; }
    float inv = 1.f / s;
    int i1 = -1, i2 = -1; float v1 = -1.f, v2 = -1.f;
#pragma unroll
    for (int e = 0; e < NEXP; e++) {
      float w = acc[e] * inv;
      if (w > v1) { v2 = v1; i2 = i1; v1 = w; i1 = e; }
      else if (w > v2) { v2 = w; i2 = e; }
    }
    int p1 = atomicAdd(&counts[i1], 1);
    tokb[i1 * BTOK + p1] = b; tokw[i1 * BTOK + p1] = v1;
    int p2 = atomicAdd(&counts[i2], 1);
    tokb[i2 * BTOK + p2] = b; tokw[i2 * BTOK + p2] = v2;
    ce[2 * b] = i1; cp[2 * b] = p1; cw[2 * b] = v1;
    ce[2 * b + 1] = i2; cp[2 * b + 1] = p2; cw[2 * b + 1] = v2;
  }
}

__global__ void k_base(const int* __restrict__ counts, int* __restrict__ base) {
  if (threadIdx.x == 0 && blockIdx.x == 0) {
    int s = 0;
    for (int e = 0; e < NEXP; e++) { base[e] = s; s += counts[e]; }
  }
}

// ---------------- GEMM1: h = relu(zbf[tok]·W1T + b1) ----------------
__global__ __launch_bounds__(256) void k_gemm1(
    const __hip_bfloat16* __restrict__ zbf, const __hip_bfloat16* __restrict__ w1t,
    const float* __restrict__ b1, const int* __restrict__ counts,
    const int* __restrict__ base, const int* __restrict__ tokb,
    __hip_bfloat16* __restrict__ hbuf, int hbase) {
  int e = blockIdx.z;
  int cnt = counts[e];
  int m0 = blockIdx.x * 128;
  if (m0 >= cnt) return;
  int n0 = blockIdx.y * 128;
  int gb = base[e];

  __shared__ __align__(16) ushort sA[128 * 64];  // unpadded, XOR-swizzled chunks
  __shared__ __align__(16) ushort sB[128 * 64];

  int tid = threadIdx.x;
  int lane = tid & 63;
  int wv = tid >> 6;
  int wmoff = (wv >> 1) * 64;
  int wnoff = (wv & 1) * 64;
  int lrow = lane & 15;
  int quad = lane >> 4;

  // staging setup: wave wv loads row-segments {wv*8+s4*32}, lane -> (subrow, phys chunk)
  int subrow = lane >> 3;
  int clog = (lane & 7) ^ subrow;  // logical chunk fetched into phys slot (lane&7)
  const ushort* zb = (const ushort*)zbf;
  const ushort* w1 = (const ushort*)w1t;
  const ushort* gA[4]; const ushort* gB[4];
#pragma unroll
  for (int s4 = 0; s4 < 4; s4++) {
    int r = wv * 8 + subrow + s4 * 32;
    int m = m0 + r; if (m >= cnt) m = cnt - 1;
    gA[s4] = zb + (size_t)tokb[e * BTOK + m] * DIM + clog * 8;
    gB[s4] = w1 + (size_t)(e * NHID + hbase + n0 + r) * DIM + clog * 8;
  }

  floatx4 acc[4][4];
#pragma unroll
  for (int i = 0; i < 4; i++)
#pragma unroll
    for (int j = 0; j < 4; j++) { floatx4 zf = {0.f,0.f,0.f,0.f}; acc[i][j] = zf; }

  for (int k0 = 0; k0 < DIM; k0 += 64) {
#pragma unroll
    for (int s4 = 0; s4 < 4; s4++) {
      int ldsrow = wv * 8 + s4 * 32;
      gload_lds16(gA[s4] + k0, sA + ldsrow * 64);
      gload_lds16(gB[s4] + k0, sB + ldsrow * 64);
    }
    __syncthreads();
#pragma unroll
    for (int kk = 0; kk < 2; kk++) {
      bf16x8 af[4], bfr[4];
#pragma unroll
      for (int i = 0; i < 4; i++) {
        int row = wmoff + i * 16 + lrow;
        int pc = (kk * 4 + quad) ^ (lrow & 7);
        uint4 t = *(const uint4*)(sA + row * 64 + pc * 8);
        af[i] = __builtin_bit_cast(bf16x8, t);
      }
#pragma unroll
      for (int j = 0; j < 4; j++) {
        int row = wnoff + j * 16 + lrow;
        int pc = (kk * 4 + quad) ^ (lrow & 7);
        uint4 t = *(const uint4*)(sB + row * 64 + pc * 8);
        bfr[j] = __builtin_bit_cast(bf16x8, t);
      }
#pragma unroll
      for (int i = 0; i < 4; i++)
#pragma unroll
        for (int j = 0; j < 4; j++)
          acc[i][j] = __builtin_amdgcn_mfma_f32_16x16x32_bf16(af[i], bfr[j], acc[i][j], 0, 0, 0);
    }
    __syncthreads();
  }

#pragma unroll
  for (int i = 0; i < 4; i++) {
    int mloc = wmoff + i * 16 + quad * 4;
#pragma unroll
    for (int r = 0; r < 4; r++) {
      int m = m0 + mloc + r;
      if (m < cnt) {
#pragma unroll
        for (int j = 0; j < 4; j++) {
          int n = n0 + wnoff + j * 16 + lrow;
          float v = acc[i][j][r] + b1[e * NHID + hbase + n];
          v = fmaxf(v, 0.f);
          hbuf[(size_t)(gb + m) * HHALF + n] = __float2bfloat16(v);
        }
      }
    }
  }
}

// ---------------- GEMM2: y[slot] (+)= h·W2T (+ b2 on pass 1) ----------------
__global__ __launch_bounds__(256) void k_gemm2(
    const __hip_bfloat16* __restrict__ hbuf, const __hip_bfloat16* __restrict__ w2t,
    const float* __restrict__ b2, const int* __restrict__ counts,
    const int* __restrict__ base, const int* __restrict__ tokb,
    const float* __restrict__ tokw, float* __restrict__ out,
    float* __restrict__ ybuf, int hbase, int pass) {
  int e = blockIdx.z;
  int cnt = counts[e];
  int m0 = blockIdx.x * 128;
  if (m0 >= cnt) return;
  int n0 = blockIdx.y * 128;
  int gb = base[e];

  __shared__ __align__(16) ushort sA[128 * 64];
  __shared__ __align__(16) ushort sB[128 * 64];
  __shared__ int ltok[128];
  __shared__ float ltw[128];

  int tid = threadIdx.x;
  if (!ybuf && tid < 128) {
    int m = m0 + tid; if (m >= cnt) m = cnt - 1;
    ltok[tid] = tokb[e * BTOK + m];
    ltw[tid]  = tokw[e * BTOK + m];
  }

  int lane = tid & 63;
  int wv = tid >> 6;
  int wmoff = (wv >> 1) * 64;
  int wnoff = (wv & 1) * 64;
  int lrow = lane & 15;
  int quad = lane >> 4;

  int subrow = lane >> 3;
  int clog = (lane & 7) ^ subrow;
  const ushort* hb = (const ushort*)hbuf;
  const ushort* w2 = (const ushort*)w2t;
  const ushort* gA[4]; const ushort* gB[4];
#pragma unroll
  for (int s4 = 0; s4 < 4; s4++) {
    int r = wv * 8 + subrow + s4 * 32;
    int mm = m0 + r; if (mm >= cnt) mm = cnt - 1;
    gA[s4] = hb + (size_t)(gb + mm) * HHALF + clog * 8;
    gB[s4] = w2 + (size_t)(e * DIM + n0 + r) * NHID + hbase + clog * 8;
  }

  floatx4 acc[4][4];
#pragma unroll
  for (int i = 0; i < 4; i++)
#pragma unroll
    for (int j = 0; j < 4; j++) { floatx4 zf = {0.f,0.f,0.f,0.f}; acc[i][j] = zf; }

  for (int k0 = 0; k0 < HHALF; k0 += 64) {
#pragma unroll
    for (int s4 = 0; s4 < 4; s4++) {
      int ldsrow = wv * 8 + s4 * 32;
      gload_lds16(gA[s4] + k0, sA + ldsrow * 64);
      gload_lds16(gB[s4] + k0, sB + ldsrow * 64);
    }
    __syncthreads();
#pragma unroll
    for (int kk = 0; kk < 2; kk++) {
      bf16x8 af[4], bfr[4];
#pragma unroll
      for (int i = 0; i < 4; i++) {
        int row = wmoff + i * 16 + lrow;
        int pc = (kk * 4 + quad) ^ (lrow & 7);
        uint4 t = *(const uint4*)(sA + row * 64 + pc * 8);
        af[i] = __builtin_bit_cast(bf16x8, t);
      }
#pragma unroll
      for (int j = 0; j < 4; j++) {
        int row = wnoff + j * 16 + lrow;
        int pc = (kk * 4 + quad) ^ (lrow & 7);
        uint4 t = *(const uint4*)(sB + row * 64 + pc * 8);
        bfr[j] = __builtin_bit_cast(bf16x8, t);
      }
#pragma unroll
      for (int i = 0; i < 4; i++)
#pragma unroll
        for (int j = 0; j < 4; j++)
          acc[i][j] = __builtin_amdgcn_mfma_f32_16x16x32_bf16(af[i], bfr[j], acc[i][j], 0, 0, 0);
    }
    __syncthreads();
  }

#pragma unroll
  for (int i = 0; i < 4; i++) {
    int mloc = wmoff + i * 16 + quad * 4;
#pragma unroll
    for (int r = 0; r < 4; r++) {
      int m = m0 + mloc + r;
      if (m < cnt) {
        if (ybuf) {
          float* yr = ybuf + (size_t)(gb + m) * DIM;
#pragma unroll
          for (int j = 0; j < 4; j++) {
            int n = n0 + wnoff + j * 16 + lrow;
            float v = acc[i][j][r];
            if (pass == 0) yr[n] = v;
            else           yr[n] += v + b2[e * DIM + n];
          }
        } else {
          int t  = ltok[mloc + r];
          float w = ltw[mloc + r];
#pragma unroll
          for (int j = 0; j < 4; j++) {
            int n = n0 + wnoff + j * 16 + lrow;
            float v = acc[i][j][r] + (pass ? b2[e * DIM + n] : 0.f);
            atomicAdd(&out[(size_t)t * DIM + n], w * v);
          }
        }
      }
    }
  }
}

// ---------------- combine: out[t] = w1*y[s1] + w2*y[s2] ----------------
__global__ __launch_bounds__(256) void k_combine(
    const float* __restrict__ ybuf, const int* __restrict__ base,
    const int* __restrict__ ce, const int* __restrict__ cp,
    const float* __restrict__ cw, float* __restrict__ out) {
  int b = blockIdx.x;
  int n = threadIdx.x * 4;
  int e1 = ce[2 * b], e2 = ce[2 * b + 1];
  int s1 = base[e1] + cp[2 * b];
  int s2 = base[e2] + cp[2 * b + 1];
  float w1 = cw[2 * b], w2 = cw[2 * b + 1];
  float4 a = *(const float4*)(ybuf + (size_t)s1 * DIM + n);
  float4 c = *(const float4*)(ybuf + (size_t)s2 * DIM + n);
  float4 o;
  o.x = w1 * a.x + w2 * c.x;
  o.y = w1 * a.y + w2 * c.y;
  o.z = w1 * a.z + w2 * c.z;
  o.w = w1 * a.w + w2 * c.w;
  *(float4*)(out + (size_t)b * DIM + n) = o;
}

extern "C" void kernel_launch(void* const* d_in, const int* in_sizes, int n_in,
                              void* d_out, int out_size, void* d_ws, size_t ws_size,
                              hipStream_t stream) {
  const float* z  = (const float*)d_in[0];
  const float* Wg = (const float*)d_in[1];
  const float* bg = (const float*)d_in[2];
  const float* W1 = (const float*)d_in[3];
  const float* b1 = (const float*)d_in[4];
  const float* W2 = (const float*)d_in[5];
  const float* b2 = (const float*)d_in[6];
  float* out = (float*)d_out;
  char* ws = (char*)d_ws;
  if (ws_size < WS_BASE) return;
  bool use_ybuf = ws_size >= WS_FULL;

  int*   counts = (int*)(ws + O_COUNTS);
  int*   base   = (int*)(ws + O_BASE);
  int*   tokb   = (int*)(ws + O_TOKB);
  float* tokw   = (float*)(ws + O_TOKW);
  int*   ce     = (int*)(ws + O_CE);
  int*   cp     = (int*)(ws + O_CP);
  float* cw     = (float*)(ws + O_CW);
  __hip_bfloat16* zbf  = (__hip_bfloat16*)(ws + O_ZBF);
  __hip_bfloat16* w1t  = (__hip_bfloat16*)(ws + O_W1T);
  __hip_bfloat16* w2t  = (__hip_bfloat16*)(ws + O_W2T);
  __hip_bfloat16* hbuf = (__hip_bfloat16*)(ws + O_HBUF);
  float* ybuf = use_ybuf ? (float*)(ws + O_YBUF) : nullptr;

  k_init<<<512, 256, 0, stream>>>(out, counts);
  k_transpose<<<dim3(NHID / 32, DIM / 32, NEXP), 256, 0, stream>>>(W1, w1t, DIM, NHID);
  k_transpose<<<dim3(DIM / 32, NHID / 32, NEXP), 256, 0, stream>>>(W2, w2t, NHID, DIM);
  k_gate<<<BTOK / 4, 256, 0, stream>>>(z, Wg, bg, counts, tokb, tokw, ce, cp, cw, zbf);
  k_base<<<1, 64, 0, stream>>>(counts, base);
  for (int half = 0; half < 2; half++) {
    k_gemm1<<<dim3(BTOK / 128, HHALF / 128, NEXP), 256, 0, stream>>>(
        zbf, w1t, b1, counts, base, tokb, hbuf, half * HHALF);
    k_gemm2<<<dim3(BTOK / 128, DIM / 128, NEXP), 256, 0, stream>>>(
        hbuf, w2t, b2, counts, base, tokb, tokw, out, ybuf, half * HHALF, half);
  }
  if (use_ybuf)
    k_combine<<<BTOK, 256, 0, stream>>>(ybuf, base, ce, cp, cw, out);
}

// Round 3
// 1105.709 us; speedup vs baseline: 1.4151x; 1.2731x over previous
//
#include <hip/hip_runtime.h>
#include <hip/hip_bf16.h>
#include <cstdint>
#include <cstddef>

#define BTOK  8192
#define DIM   1024
#define NEXP  8
#define NHID  4096
#define HHALF 2048

typedef __bf16 bf16x8 __attribute__((ext_vector_type(8)));
typedef float  floatx4 __attribute__((ext_vector_type(4)));

// ---- workspace layout (bytes) ----
#define O_COUNTS 0
#define O_BASE   256
#define O_TOKB   1024
#define O_TOKW   (O_TOKB + (size_t)NEXP*BTOK*4)
#define O_CE     (O_TOKW + (size_t)NEXP*BTOK*4)
#define O_CP     (O_CE + (size_t)2*BTOK*4)
#define O_CW     (O_CP + (size_t)2*BTOK*4)
#define O_ZBF    (O_CW + (size_t)2*BTOK*4)
#define O_W1T    (O_ZBF + (size_t)BTOK*DIM*2)
#define O_W2T    (O_W1T + (size_t)NEXP*DIM*NHID*2)
#define O_HBUF   (O_W2T + (size_t)NEXP*DIM*NHID*2)
#define WS_BASE  (O_HBUF + (size_t)2*BTOK*HHALF*2)     // ~218.8 MB (atomic fallback)
#define O_YBUF   WS_BASE
#define WS_FULL  (O_YBUF + (size_t)2*BTOK*DIM*4)       // ~286 MB (ybuf path)

__device__ __forceinline__ void gload_lds16(const void* g, void* l) {
  __builtin_amdgcn_global_load_lds(
      (const __attribute__((address_space(1))) void*)g,
      (__attribute__((address_space(3))) void*)l, 16, 0, 0);
}

// ---------------- zero counters ----------------
__global__ void k_zcnt(int* __restrict__ counts) {
  if (threadIdx.x < NEXP) counts[threadIdx.x] = 0;
}

// ---------------- zero out (fallback/atomic path only) ----------------
__global__ void k_zout(float* __restrict__ out) {
  int i = blockIdx.x * blockDim.x + threadIdx.x;
  float4 z4 = {0.f, 0.f, 0.f, 0.f};
  float4* o = (float4*)out;
  int n = BTOK * DIM / 4;
  for (int j = i; j < n; j += gridDim.x * blockDim.x) o[j] = z4;
}

// ---------------- transpose fp32 [Z][R][C] -> bf16 [Z][C][R] ----------------
__global__ __launch_bounds__(256) void k_transpose(
    const float* __restrict__ src, __hip_bfloat16* __restrict__ dst, int R, int C) {
  __shared__ float tile[32][33];
  int zz = blockIdx.z;
  const float* s = src + (size_t)zz * R * C;
  __hip_bfloat16* d = dst + (size_t)zz * R * C;
  int c0 = blockIdx.x * 32, r0 = blockIdx.y * 32;
  int tx = threadIdx.x & 31, ty = threadIdx.x >> 5;
#pragma unroll
  for (int i = ty; i < 32; i += 8)
    tile[i][tx] = s[(size_t)(r0 + i) * C + c0 + tx];
  __syncthreads();
#pragma unroll
  for (int i = ty; i < 32; i += 8)
    d[(size_t)(c0 + i) * R + r0 + tx] = __float2bfloat16(tile[tx][i]);
}

// ---------------- gating ----------------
__global__ __launch_bounds__(256) void k_gate(
    const float* __restrict__ z, const float* __restrict__ Wg,
    const float* __restrict__ bg, int* __restrict__ counts,
    int* __restrict__ tokb, float* __restrict__ tokw,
    int* __restrict__ ce, int* __restrict__ cp, float* __restrict__ cw,
    __hip_bfloat16* __restrict__ zbf) {
  __shared__ float wgT[NEXP * DIM];
  int tid = threadIdx.x;
  for (int i = tid; i < NEXP * DIM; i += 256) {
    int d = i >> 3, e = i & 7;
    wgT[e * DIM + d] = Wg[i];
  }
  __syncthreads();
  int lane = tid & 63;
  int b = blockIdx.x * 4 + (tid >> 6);
  const float* zr = z + (size_t)b * DIM;
  float zv[16];
#pragma unroll
  for (int i = 0; i < 16; i++) zv[i] = zr[lane + 64 * i];
  __hip_bfloat16* zb = zbf + (size_t)b * DIM;
#pragma unroll
  for (int i = 0; i < 16; i++) zb[lane + 64 * i] = __float2bfloat16(zv[i]);
  float acc[NEXP];
#pragma unroll
  for (int e = 0; e < NEXP; e++) {
    float a = 0.f;
#pragma unroll
    for (int i = 0; i < 16; i++) a += zv[i] * wgT[e * DIM + lane + 64 * i];
    acc[e] = a;
  }
#pragma unroll
  for (int off = 32; off > 0; off >>= 1) {
#pragma unroll
    for (int e = 0; e < NEXP; e++) acc[e] += __shfl_down(acc[e], off);
  }
  if (lane == 0) {
    float mx = -1e30f;
#pragma unroll
    for (int e = 0; e < NEXP; e++) { acc[e] += bg[e]; mx = fmaxf(mx, acc[e]); }
    float s = 0.f;
#pragma unroll
    for (int e = 0; e < NEXP; e++) { acc[e] = expf(acc[e] - mx); s += acc[e]; }
    float inv = 1.f / s;
    int i1 = -1, i2 = -1; float v1 = -1.f, v2 = -1.f;
#pragma unroll
    for (int e = 0; e < NEXP; e++) {
      float w = acc[e] * inv;
      if (w > v1) { v2 = v1; i2 = i1; v1 = w; i1 = e; }
      else if (w > v2) { v2 = w; i2 = e; }
    }
    int p1 = atomicAdd(&counts[i1], 1);
    tokb[i1 * BTOK + p1] = b; tokw[i1 * BTOK + p1] = v1;
    int p2 = atomicAdd(&counts[i2], 1);
    tokb[i2 * BTOK + p2] = b; tokw[i2 * BTOK + p2] = v2;
    ce[2 * b] = i1; cp[2 * b] = p1; cw[2 * b] = v1;
    ce[2 * b + 1] = i2; cp[2 * b + 1] = p2; cw[2 * b + 1] = v2;
  }
}

__global__ void k_base(const int* __restrict__ counts, int* __restrict__ base) {
  if (threadIdx.x == 0 && blockIdx.x == 0) {
    int s = 0;
    for (int e = 0; e < NEXP; e++) { base[e] = s; s += counts[e]; }
  }
}

// ---------------- GEMM1: h = relu(zbf[tok]·W1T + b1) ----------------
__global__ __launch_bounds__(256, 3) void k_gemm1(
    const __hip_bfloat16* __restrict__ zbf, const __hip_bfloat16* __restrict__ w1t,
    const float* __restrict__ b1, const int* __restrict__ counts,
    const int* __restrict__ base, const int* __restrict__ tokb,
    __hip_bfloat16* __restrict__ hbuf, int hbase) {
  int e = blockIdx.z;
  int cnt = counts[e];
  int n0 = blockIdx.y * 128;
  int gb = base[e];

  __shared__ __align__(16) ushort sA[128 * 64];  // LDS = exactly 32 KB total
  __shared__ __align__(16) ushort sB[128 * 64];

  int tid = threadIdx.x;
  int lane = tid & 63;
  int wv = tid >> 6;
  int wmoff = (wv >> 1) * 64;
  int wnoff = (wv & 1) * 64;
  int lrow = lane & 15;
  int quad = lane >> 4;
  int subrow = lane >> 3;
  int clog = (lane & 7) ^ subrow;  // XOR chunk swizzle (conflict-free frag reads)

  const ushort* zb = (const ushort*)zbf;
  const ushort* w1 = (const ushort*)w1t;
  const ushort* gB[4];
#pragma unroll
  for (int s4 = 0; s4 < 4; s4++) {
    int r = wv * 8 + subrow + s4 * 32;
    gB[s4] = w1 + (size_t)(e * NHID + hbase + n0 + r) * DIM + clog * 8;
  }

  for (int mt = blockIdx.x; mt * 128 < cnt; mt += gridDim.x) {
    int m0 = mt * 128;
    const ushort* gA[4];
#pragma unroll
    for (int s4 = 0; s4 < 4; s4++) {
      int r = wv * 8 + subrow + s4 * 32;
      int m = m0 + r; if (m >= cnt) m = cnt - 1;
      gA[s4] = zb + (size_t)tokb[e * BTOK + m] * DIM + clog * 8;
    }

    floatx4 acc[4][4];
#pragma unroll
    for (int i = 0; i < 4; i++)
#pragma unroll
      for (int j = 0; j < 4; j++) { floatx4 zf = {0.f,0.f,0.f,0.f}; acc[i][j] = zf; }

    for (int k0 = 0; k0 < DIM; k0 += 64) {
#pragma unroll
      for (int s4 = 0; s4 < 4; s4++) {
        int ldsrow = wv * 8 + s4 * 32;
        gload_lds16(gA[s4] + k0, sA + ldsrow * 64);
        gload_lds16(gB[s4] + k0, sB + ldsrow * 64);
      }
      __syncthreads();
#pragma unroll
      for (int kk = 0; kk < 2; kk++) {
        bf16x8 af[4], bfr[4];
#pragma unroll
        for (int i = 0; i < 4; i++) {
          int row = wmoff + i * 16 + lrow;
          int pc = (kk * 4 + quad) ^ (lrow & 7);
          uint4 t = *(const uint4*)(sA + row * 64 + pc * 8);
          af[i] = __builtin_bit_cast(bf16x8, t);
        }
#pragma unroll
        for (int j = 0; j < 4; j++) {
          int row = wnoff + j * 16 + lrow;
          int pc = (kk * 4 + quad) ^ (lrow & 7);
          uint4 t = *(const uint4*)(sB + row * 64 + pc * 8);
          bfr[j] = __builtin_bit_cast(bf16x8, t);
        }
#pragma unroll
        for (int i = 0; i < 4; i++)
#pragma unroll
          for (int j = 0; j < 4; j++)
            acc[i][j] = __builtin_amdgcn_mfma_f32_16x16x32_bf16(af[i], bfr[j], acc[i][j], 0, 0, 0);
      }
      __syncthreads();
    }

#pragma unroll
    for (int i = 0; i < 4; i++) {
      int mloc = wmoff + i * 16 + quad * 4;
#pragma unroll
      for (int r = 0; r < 4; r++) {
        int m = m0 + mloc + r;
        if (m < cnt) {
#pragma unroll
          for (int j = 0; j < 4; j++) {
            int n = n0 + wnoff + j * 16 + lrow;
            float v = acc[i][j][r] + b1[e * NHID + hbase + n];
            v = fmaxf(v, 0.f);
            hbuf[(size_t)(gb + m) * HHALF + n] = __float2bfloat16(v);
          }
        }
      }
    }
  }
}

// ---------------- GEMM2: y[slot] (+)= h·W2T (+ b2 on pass 1) ----------------
__global__ __launch_bounds__(256, 3) void k_gemm2(
    const __hip_bfloat16* __restrict__ hbuf, const __hip_bfloat16* __restrict__ w2t,
    const float* __restrict__ b2, const int* __restrict__ counts,
    const int* __restrict__ base, const int* __restrict__ tokb,
    const float* __restrict__ tokw, float* __restrict__ out,
    float* __restrict__ ybuf, int hbase, int pass) {
  int e = blockIdx.z;
  int cnt = counts[e];
  int n0 = blockIdx.y * 128;
  int gb = base[e];

  __shared__ __align__(16) ushort sA[128 * 64];
  __shared__ __align__(16) ushort sB[128 * 64];

  int tid = threadIdx.x;
  int lane = tid & 63;
  int wv = tid >> 6;
  int wmoff = (wv >> 1) * 64;
  int wnoff = (wv & 1) * 64;
  int lrow = lane & 15;
  int quad = lane >> 4;
  int subrow = lane >> 3;
  int clog = (lane & 7) ^ subrow;

  const ushort* hb = (const ushort*)hbuf;
  const ushort* w2 = (const ushort*)w2t;
  const ushort* gB[4];
#pragma unroll
  for (int s4 = 0; s4 < 4; s4++) {
    int r = wv * 8 + subrow + s4 * 32;
    gB[s4] = w2 + (size_t)(e * DIM + n0 + r) * NHID + hbase + clog * 8;
  }

  for (int mt = blockIdx.x; mt * 128 < cnt; mt += gridDim.x) {
    int m0 = mt * 128;
    const ushort* gA[4];
#pragma unroll
    for (int s4 = 0; s4 < 4; s4++) {
      int r = wv * 8 + subrow + s4 * 32;
      int mm = m0 + r; if (mm >= cnt) mm = cnt - 1;
      gA[s4] = hb + (size_t)(gb + mm) * HHALF + clog * 8;
    }

    floatx4 acc[4][4];
#pragma unroll
    for (int i = 0; i < 4; i++)
#pragma unroll
      for (int j = 0; j < 4; j++) { floatx4 zf = {0.f,0.f,0.f,0.f}; acc[i][j] = zf; }

    for (int k0 = 0; k0 < HHALF; k0 += 64) {
#pragma unroll
      for (int s4 = 0; s4 < 4; s4++) {
        int ldsrow = wv * 8 + s4 * 32;
        gload_lds16(gA[s4] + k0, sA + ldsrow * 64);
        gload_lds16(gB[s4] + k0, sB + ldsrow * 64);
      }
      __syncthreads();
#pragma unroll
      for (int kk = 0; kk < 2; kk++) {
        bf16x8 af[4], bfr[4];
#pragma unroll
        for (int i = 0; i < 4; i++) {
          int row = wmoff + i * 16 + lrow;
          int pc = (kk * 4 + quad) ^ (lrow & 7);
          uint4 t = *(const uint4*)(sA + row * 64 + pc * 8);
          af[i] = __builtin_bit_cast(bf16x8, t);
        }
#pragma unroll
        for (int j = 0; j < 4; j++) {
          int row = wnoff + j * 16 + lrow;
          int pc = (kk * 4 + quad) ^ (lrow & 7);
          uint4 t = *(const uint4*)(sB + row * 64 + pc * 8);
          bfr[j] = __builtin_bit_cast(bf16x8, t);
        }
#pragma unroll
        for (int i = 0; i < 4; i++)
#pragma unroll
          for (int j = 0; j < 4; j++)
            acc[i][j] = __builtin_amdgcn_mfma_f32_16x16x32_bf16(af[i], bfr[j], acc[i][j], 0, 0, 0);
      }
      __syncthreads();
    }

#pragma unroll
    for (int i = 0; i < 4; i++) {
      int mloc = wmoff + i * 16 + quad * 4;
#pragma unroll
      for (int r = 0; r < 4; r++) {
        int m = m0 + mloc + r;
        if (m < cnt) {
          if (ybuf) {
            float* yr = ybuf + (size_t)(gb + m) * DIM;
#pragma unroll
            for (int j = 0; j < 4; j++) {
              int n = n0 + wnoff + j * 16 + lrow;
              float v = acc[i][j][r];
              if (pass == 0) yr[n] = v;
              else           yr[n] += v + b2[e * DIM + n];
            }
          } else {
            int t  = tokb[e * BTOK + m];
            float w = tokw[e * BTOK + m];
#pragma unroll
            for (int j = 0; j < 4; j++) {
              int n = n0 + wnoff + j * 16 + lrow;
              float v = acc[i][j][r] + (pass ? b2[e * DIM + n] : 0.f);
              atomicAdd(&out[(size_t)t * DIM + n], w * v);
            }
          }
        }
      }
    }
  }
}

// ---------------- combine: out[t] = w1*y[s1] + w2*y[s2] ----------------
__global__ __launch_bounds__(256) void k_combine(
    const float* __restrict__ ybuf, const int* __restrict__ base,
    const int* __restrict__ ce, const int* __restrict__ cp,
    const float* __restrict__ cw, float* __restrict__ out) {
  int b = blockIdx.x;
  int n = threadIdx.x * 4;
  int e1 = ce[2 * b], e2 = ce[2 * b + 1];
  int s1 = base[e1] + cp[2 * b];
  int s2 = base[e2] + cp[2 * b + 1];
  float w1 = cw[2 * b], w2 = cw[2 * b + 1];
  float4 a = *(const float4*)(ybuf + (size_t)s1 * DIM + n);
  float4 c = *(const float4*)(ybuf + (size_t)s2 * DIM + n);
  float4 o;
  o.x = w1 * a.x + w2 * c.x;
  o.y = w1 * a.y + w2 * c.y;
  o.z = w1 * a.z + w2 * c.z;
  o.w = w1 * a.w + w2 * c.w;
  *(float4*)(out + (size_t)b * DIM + n) = o;
}

extern "C" void kernel_launch(void* const* d_in, const int* in_sizes, int n_in,
                              void* d_out, int out_size, void* d_ws, size_t ws_size,
                              hipStream_t stream) {
  const float* z  = (const float*)d_in[0];
  const float* Wg = (const float*)d_in[1];
  const float* bg = (const float*)d_in[2];
  const float* W1 = (const float*)d_in[3];
  const float* b1 = (const float*)d_in[4];
  const float* W2 = (const float*)d_in[5];
  const float* b2 = (const float*)d_in[6];
  float* out = (float*)d_out;
  char* ws = (char*)d_ws;
  if (ws_size < WS_BASE) return;
  bool use_ybuf = ws_size >= WS_FULL;

  int*   counts = (int*)(ws + O_COUNTS);
  int*   base   = (int*)(ws + O_BASE);
  int*   tokb   = (int*)(ws + O_TOKB);
  float* tokw   = (float*)(ws + O_TOKW);
  int*   ce     = (int*)(ws + O_CE);
  int*   cp     = (int*)(ws + O_CP);
  float* cw     = (float*)(ws + O_CW);
  __hip_bfloat16* zbf  = (__hip_bfloat16*)(ws + O_ZBF);
  __hip_bfloat16* w1t  = (__hip_bfloat16*)(ws + O_W1T);
  __hip_bfloat16* w2t  = (__hip_bfloat16*)(ws + O_W2T);
  __hip_bfloat16* hbuf = (__hip_bfloat16*)(ws + O_HBUF);
  float* ybuf = use_ybuf ? (float*)(ws + O_YBUF) : nullptr;

  k_zcnt<<<1, 64, 0, stream>>>(counts);
  if (!use_ybuf) k_zout<<<512, 256, 0, stream>>>(out);
  k_transpose<<<dim3(NHID / 32, DIM / 32, NEXP), 256, 0, stream>>>(W1, w1t, DIM, NHID);
  k_transpose<<<dim3(DIM / 32, NHID / 32, NEXP), 256, 0, stream>>>(W2, w2t, NHID, DIM);
  k_gate<<<BTOK / 4, 256, 0, stream>>>(z, Wg, bg, counts, tokb, tokw, ce, cp, cw, zbf);
  k_base<<<1, 64, 0, stream>>>(counts, base);
  for (int half = 0; half < 2; half++) {
    k_gemm1<<<dim3(16, HHALF / 128, NEXP), 256, 0, stream>>>(
        zbf, w1t, b1, counts, base, tokb, hbuf, half * HHALF);
    k_gemm2<<<dim3(16, DIM / 128, NEXP), 256, 0, stream>>>(
        hbuf, w2t, b2, counts, base, tokb, tokw, out, ybuf, half * HHALF, half);
  }
  if (use_ybuf)
    k_combine<<<BTOK, 256, 0, stream>>>(ybuf, base, ce, cp, cw, out);
}

// Round 4
// 940.678 us; speedup vs baseline: 1.6634x; 1.1754x over previous
//
#include <hip/hip_runtime.h>
#include <hip/hip_bf16.h>
#include <cstdint>
#include <cstddef>

#define BTOK  8192
#define DIM   1024
#define NEXP  8
#define NHID  4096
#define HHALF 2048
#define GATE_TOK 64

typedef __bf16 bf16x8 __attribute__((ext_vector_type(8)));
typedef float  floatx4 __attribute__((ext_vector_type(4)));

// ---- workspace layout (bytes) ----
#define O_COUNTS 0
#define O_BASE   256
#define O_TOKB   1024
#define O_TOKW   (O_TOKB + (size_t)NEXP*BTOK*4)
#define O_CE     (O_TOKW + (size_t)NEXP*BTOK*4)
#define O_CP     (O_CE + (size_t)2*BTOK*4)
#define O_CW     (O_CP + (size_t)2*BTOK*4)
#define O_ZBF    (O_CW + (size_t)2*BTOK*4)
#define O_W1T    (O_ZBF + (size_t)BTOK*DIM*2)
#define O_W2T    (O_W1T + (size_t)NEXP*DIM*NHID*2)
#define O_HBUF   (O_W2T + (size_t)NEXP*DIM*NHID*2)
#define WS_BASE  (O_HBUF + (size_t)2*BTOK*HHALF*2)     // ~218.8 MB (atomic fallback)
#define O_YBUF   WS_BASE
#define WS_FULL  (O_YBUF + (size_t)2*BTOK*DIM*4)       // ~286 MB (ybuf path)

__device__ __forceinline__ void gload_lds16(const void* g, void* l) {
  __builtin_amdgcn_global_load_lds(
      (const __attribute__((address_space(1))) void*)g,
      (__attribute__((address_space(3))) void*)l, 16, 0, 0);
}

__device__ __forceinline__ ushort f2bf(float x) {
  return __builtin_bit_cast(ushort, __float2bfloat16(x));
}

// ---------------- zero counters ----------------
__global__ void k_zcnt(int* __restrict__ counts) {
  if (threadIdx.x < NEXP) counts[threadIdx.x] = 0;
}

// ---------------- zero out (fallback/atomic path only) ----------------
__global__ void k_zout(float* __restrict__ out) {
  int i = blockIdx.x * blockDim.x + threadIdx.x;
  float4 z4 = {0.f, 0.f, 0.f, 0.f};
  float4* o = (float4*)out;
  int n = BTOK * DIM / 4;
  for (int j = i; j < n; j += gridDim.x * blockDim.x) o[j] = z4;
}

// ---------------- transpose fp32 [Z][R][C] -> bf16 [Z][C][R] ----------------
__global__ __launch_bounds__(256) void k_transpose(
    const float* __restrict__ src, __hip_bfloat16* __restrict__ dst, int R, int C) {
  __shared__ float tile[32][33];
  int zz = blockIdx.z;
  const float* s = src + (size_t)zz * R * C;
  __hip_bfloat16* d = dst + (size_t)zz * R * C;
  int c0 = blockIdx.x * 32, r0 = blockIdx.y * 32;
  int tx = threadIdx.x & 31, ty = threadIdx.x >> 5;
#pragma unroll
  for (int i = ty; i < 32; i += 8)
    tile[i][tx] = s[(size_t)(r0 + i) * C + c0 + tx];
  __syncthreads();
#pragma unroll
  for (int i = ty; i < 32; i += 8)
    d[(size_t)(c0 + i) * R + r0 + tx] = __float2bfloat16(tile[tx][i]);
}

// ---------------- gating: block of 64 tokens, LDS histogram, 8 atomics/block ----------------
__global__ __launch_bounds__(256) void k_gate(
    const float* __restrict__ z, const float* __restrict__ Wg,
    const float* __restrict__ bg, int* __restrict__ counts,
    int* __restrict__ tokb, float* __restrict__ tokw,
    int* __restrict__ ce, int* __restrict__ cp, float* __restrict__ cw,
    __hip_bfloat16* __restrict__ zbf) {
  __shared__ float wgT[NEXP * DIM];       // [e][d]
  __shared__ int   le[2 * GATE_TOK];
  __shared__ float lw[2 * GATE_TOK];
  __shared__ int   lr[2 * GATE_TOK];
  __shared__ int   lcnt[NEXP];
  __shared__ int   gbase[NEXP];

  int tid = threadIdx.x;
  if (tid < NEXP) lcnt[tid] = 0;
  // stage Wg transposed; lane-consecutive d -> conflict-free LDS stores
#pragma unroll
  for (int e = 0; e < NEXP; e++)
    for (int d = tid; d < DIM; d += 256)
      wgT[e * DIM + d] = Wg[d * NEXP + e];
  __syncthreads();

  int lane = tid & 63;
  int wv = tid >> 6;
  int b0 = blockIdx.x * GATE_TOK;

  for (int t = 0; t < 16; t++) {
    int lt = wv * 16 + t;
    int b = b0 + lt;
    const float4* zr4 = (const float4*)(z + (size_t)b * DIM);
    float4 zv[4];
#pragma unroll
    for (int i = 0; i < 4; i++) zv[i] = zr4[lane + 64 * i];
    ushort4* zb4 = (ushort4*)((ushort*)zbf + (size_t)b * DIM);
#pragma unroll
    for (int i = 0; i < 4; i++) {
      ushort4 u;
      u.x = f2bf(zv[i].x); u.y = f2bf(zv[i].y);
      u.z = f2bf(zv[i].z); u.w = f2bf(zv[i].w);
      zb4[lane + 64 * i] = u;
    }
    float acc[NEXP];
#pragma unroll
    for (int e = 0; e < NEXP; e++) acc[e] = 0.f;
#pragma unroll
    for (int e = 0; e < NEXP; e++) {
      const float4* wg4 = (const float4*)(wgT + e * DIM);
#pragma unroll
      for (int i = 0; i < 4; i++) {
        float4 w4 = wg4[lane + 64 * i];
        acc[e] += zv[i].x * w4.x + zv[i].y * w4.y + zv[i].z * w4.z + zv[i].w * w4.w;
      }
    }
#pragma unroll
    for (int off = 32; off > 0; off >>= 1) {
#pragma unroll
      for (int e = 0; e < NEXP; e++) acc[e] += __shfl_down(acc[e], off);
    }
    if (lane == 0) {
      float mx = -1e30f;
#pragma unroll
      for (int e = 0; e < NEXP; e++) { acc[e] += bg[e]; mx = fmaxf(mx, acc[e]); }
      float s = 0.f;
#pragma unroll
      for (int e = 0; e < NEXP; e++) { acc[e] = expf(acc[e] - mx); s += acc[e]; }
      float inv = 1.f / s;
      int i1 = -1, i2 = -1; float v1 = -1.f, v2 = -1.f;
#pragma unroll
      for (int e = 0; e < NEXP; e++) {   // stable: first index wins ties (lax.top_k)
        float w = acc[e] * inv;
        if (w > v1) { v2 = v1; i2 = i1; v1 = w; i1 = e; }
        else if (w > v2) { v2 = w; i2 = e; }
      }
      le[2 * lt] = i1;     lw[2 * lt] = v1;
      le[2 * lt + 1] = i2; lw[2 * lt + 1] = v2;
    }
  }
  __syncthreads();
  if (tid < 2 * GATE_TOK) lr[tid] = atomicAdd(&lcnt[le[tid]], 1);
  __syncthreads();
  if (tid < NEXP) gbase[tid] = atomicAdd(&counts[tid], lcnt[tid]);
  __syncthreads();
  if (tid < 2 * GATE_TOK) {
    int e = le[tid];
    int p = gbase[e] + lr[tid];
    int b = b0 + (tid >> 1);
    int slot = tid & 1;
    tokb[e * BTOK + p] = b;
    tokw[e * BTOK + p] = lw[tid];
    ce[2 * b + slot] = e;
    cp[2 * b + slot] = p;
    cw[2 * b + slot] = lw[tid];
  }
}

__global__ void k_base(const int* __restrict__ counts, int* __restrict__ base) {
  if (threadIdx.x == 0 && blockIdx.x == 0) {
    int s = 0;
    for (int e = 0; e < NEXP; e++) { base[e] = s; s += counts[e]; }
  }
}

// ---------------- GEMM1: h = relu(zbf[tok]·W1T + b1) ----------------
__global__ __launch_bounds__(256, 3) void k_gemm1(
    const __hip_bfloat16* __restrict__ zbf, const __hip_bfloat16* __restrict__ w1t,
    const float* __restrict__ b1, const int* __restrict__ counts,
    const int* __restrict__ base, const int* __restrict__ tokb,
    __hip_bfloat16* __restrict__ hbuf, int hbase) {
  int e = blockIdx.z;
  int cnt = counts[e];
  int n0 = blockIdx.y * 128;
  int gb = base[e];

  __shared__ __align__(16) ushort sA[128 * 64];  // LDS = exactly 32 KB total
  __shared__ __align__(16) ushort sB[128 * 64];

  int tid = threadIdx.x;
  int lane = tid & 63;
  int wv = tid >> 6;
  int wmoff = (wv >> 1) * 64;
  int wnoff = (wv & 1) * 64;
  int lrow = lane & 15;
  int quad = lane >> 4;
  int subrow = lane >> 3;
  int clog = (lane & 7) ^ subrow;  // XOR chunk swizzle (conflict-free frag reads)

  const ushort* zb = (const ushort*)zbf;
  const ushort* w1 = (const ushort*)w1t;
  const ushort* gB[4];
#pragma unroll
  for (int s4 = 0; s4 < 4; s4++) {
    int r = wv * 8 + subrow + s4 * 32;
    gB[s4] = w1 + (size_t)(e * NHID + hbase + n0 + r) * DIM + clog * 8;
  }

  for (int mt = blockIdx.x; mt * 128 < cnt; mt += gridDim.x) {
    int m0 = mt * 128;
    const ushort* gA[4];
#pragma unroll
    for (int s4 = 0; s4 < 4; s4++) {
      int r = wv * 8 + subrow + s4 * 32;
      int m = m0 + r; if (m >= cnt) m = cnt - 1;
      gA[s4] = zb + (size_t)tokb[e * BTOK + m] * DIM + clog * 8;
    }

    floatx4 acc[4][4];
#pragma unroll
    for (int i = 0; i < 4; i++)
#pragma unroll
      for (int j = 0; j < 4; j++) { floatx4 zf = {0.f,0.f,0.f,0.f}; acc[i][j] = zf; }

    for (int k0 = 0; k0 < DIM; k0 += 64) {
#pragma unroll
      for (int s4 = 0; s4 < 4; s4++) {
        int ldsrow = wv * 8 + s4 * 32;
        gload_lds16(gA[s4] + k0, sA + ldsrow * 64);
        gload_lds16(gB[s4] + k0, sB + ldsrow * 64);
      }
      __syncthreads();
#pragma unroll
      for (int kk = 0; kk < 2; kk++) {
        bf16x8 af[4], bfr[4];
#pragma unroll
        for (int i = 0; i < 4; i++) {
          int row = wmoff + i * 16 + lrow;
          int pc = (kk * 4 + quad) ^ (lrow & 7);
          uint4 t = *(const uint4*)(sA + row * 64 + pc * 8);
          af[i] = __builtin_bit_cast(bf16x8, t);
        }
#pragma unroll
        for (int j = 0; j < 4; j++) {
          int row = wnoff + j * 16 + lrow;
          int pc = (kk * 4 + quad) ^ (lrow & 7);
          uint4 t = *(const uint4*)(sB + row * 64 + pc * 8);
          bfr[j] = __builtin_bit_cast(bf16x8, t);
        }
#pragma unroll
        for (int i = 0; i < 4; i++)
#pragma unroll
          for (int j = 0; j < 4; j++)
            acc[i][j] = __builtin_amdgcn_mfma_f32_16x16x32_bf16(af[i], bfr[j], acc[i][j], 0, 0, 0);
      }
      __syncthreads();
    }

#pragma unroll
    for (int i = 0; i < 4; i++) {
      int mloc = wmoff + i * 16 + quad * 4;
#pragma unroll
      for (int r = 0; r < 4; r++) {
        int m = m0 + mloc + r;
        if (m < cnt) {
#pragma unroll
          for (int j = 0; j < 4; j++) {
            int n = n0 + wnoff + j * 16 + lrow;
            float v = acc[i][j][r] + b1[e * NHID + hbase + n];
            v = fmaxf(v, 0.f);
            hbuf[(size_t)(gb + m) * HHALF + n] = __float2bfloat16(v);
          }
        }
      }
    }
  }
}

// ---------------- GEMM2: y[slot] (+)= h·W2T (+ b2 on pass 1) ----------------
__global__ __launch_bounds__(256, 3) void k_gemm2(
    const __hip_bfloat16* __restrict__ hbuf, const __hip_bfloat16* __restrict__ w2t,
    const float* __restrict__ b2, const int* __restrict__ counts,
    const int* __restrict__ base, const int* __restrict__ tokb,
    const float* __restrict__ tokw, float* __restrict__ out,
    float* __restrict__ ybuf, int hbase, int pass) {
  int e = blockIdx.z;
  int cnt = counts[e];
  int n0 = blockIdx.y * 128;
  int gb = base[e];

  __shared__ __align__(16) ushort sA[128 * 64];
  __shared__ __align__(16) ushort sB[128 * 64];

  int tid = threadIdx.x;
  int lane = tid & 63;
  int wv = tid >> 6;
  int wmoff = (wv >> 1) * 64;
  int wnoff = (wv & 1) * 64;
  int lrow = lane & 15;
  int quad = lane >> 4;
  int subrow = lane >> 3;
  int clog = (lane & 7) ^ subrow;

  const ushort* hb = (const ushort*)hbuf;
  const ushort* w2 = (const ushort*)w2t;
  const ushort* gB[4];
#pragma unroll
  for (int s4 = 0; s4 < 4; s4++) {
    int r = wv * 8 + subrow + s4 * 32;
    gB[s4] = w2 + (size_t)(e * DIM + n0 + r) * NHID + hbase + clog * 8;
  }

  for (int mt = blockIdx.x; mt * 128 < cnt; mt += gridDim.x) {
    int m0 = mt * 128;
    const ushort* gA[4];
#pragma unroll
    for (int s4 = 0; s4 < 4; s4++) {
      int r = wv * 8 + subrow + s4 * 32;
      int mm = m0 + r; if (mm >= cnt) mm = cnt - 1;
      gA[s4] = hb + (size_t)(gb + mm) * HHALF + clog * 8;
    }

    floatx4 acc[4][4];
#pragma unroll
    for (int i = 0; i < 4; i++)
#pragma unroll
      for (int j = 0; j < 4; j++) { floatx4 zf = {0.f,0.f,0.f,0.f}; acc[i][j] = zf; }

    for (int k0 = 0; k0 < HHALF; k0 += 64) {
#pragma unroll
      for (int s4 = 0; s4 < 4; s4++) {
        int ldsrow = wv * 8 + s4 * 32;
        gload_lds16(gA[s4] + k0, sA + ldsrow * 64);
        gload_lds16(gB[s4] + k0, sB + ldsrow * 64);
      }
      __syncthreads();
#pragma unroll
      for (int kk = 0; kk < 2; kk++) {
        bf16x8 af[4], bfr[4];
#pragma unroll
        for (int i = 0; i < 4; i++) {
          int row = wmoff + i * 16 + lrow;
          int pc = (kk * 4 + quad) ^ (lrow & 7);
          uint4 t = *(const uint4*)(sA + row * 64 + pc * 8);
          af[i] = __builtin_bit_cast(bf16x8, t);
        }
#pragma unroll
        for (int j = 0; j < 4; j++) {
          int row = wnoff + j * 16 + lrow;
          int pc = (kk * 4 + quad) ^ (lrow & 7);
          uint4 t = *(const uint4*)(sB + row * 64 + pc * 8);
          bfr[j] = __builtin_bit_cast(bf16x8, t);
        }
#pragma unroll
        for (int i = 0; i < 4; i++)
#pragma unroll
          for (int j = 0; j < 4; j++)
            acc[i][j] = __builtin_amdgcn_mfma_f32_16x16x32_bf16(af[i], bfr[j], acc[i][j], 0, 0, 0);
      }
      __syncthreads();
    }

#pragma unroll
    for (int i = 0; i < 4; i++) {
      int mloc = wmoff + i * 16 + quad * 4;
#pragma unroll
      for (int r = 0; r < 4; r++) {
        int m = m0 + mloc + r;
        if (m < cnt) {
          if (ybuf) {
            float* yr = ybuf + (size_t)(gb + m) * DIM;
#pragma unroll
            for (int j = 0; j < 4; j++) {
              int n = n0 + wnoff + j * 16 + lrow;
              float v = acc[i][j][r];
              if (pass == 0) yr[n] = v;
              else           yr[n] += v + b2[e * DIM + n];
            }
          } else {
            int t  = tokb[e * BTOK + m];
            float w = tokw[e * BTOK + m];
#pragma unroll
            for (int j = 0; j < 4; j++) {
              int n = n0 + wnoff + j * 16 + lrow;
              float v = acc[i][j][r] + (pass ? b2[e * DIM + n] : 0.f);
              atomicAdd(&out[(size_t)t * DIM + n], w * v);
            }
          }
        }
      }
    }
  }
}

// ---------------- combine: out[t] = w1*y[s1] + w2*y[s2] ----------------
__global__ __launch_bounds__(256) void k_combine(
    const float* __restrict__ ybuf, const int* __restrict__ base,
    const int* __restrict__ ce, const int* __restrict__ cp,
    const float* __restrict__ cw, float* __restrict__ out) {
  int b = blockIdx.x;
  int n = threadIdx.x * 4;
  int e1 = ce[2 * b], e2 = ce[2 * b + 1];
  int s1 = base[e1] + cp[2 * b];
  int s2 = base[e2] + cp[2 * b + 1];
  float w1 = cw[2 * b], w2 = cw[2 * b + 1];
  float4 a = *(const float4*)(ybuf + (size_t)s1 * DIM + n);
  float4 c = *(const float4*)(ybuf + (size_t)s2 * DIM + n);
  float4 o;
  o.x = w1 * a.x + w2 * c.x;
  o.y = w1 * a.y + w2 * c.y;
  o.z = w1 * a.z + w2 * c.z;
  o.w = w1 * a.w + w2 * c.w;
  *(float4*)(out + (size_t)b * DIM + n) = o;
}

extern "C" void kernel_launch(void* const* d_in, const int* in_sizes, int n_in,
                              void* d_out, int out_size, void* d_ws, size_t ws_size,
                              hipStream_t stream) {
  const float* z  = (const float*)d_in[0];
  const float* Wg = (const float*)d_in[1];
  const float* bg = (const float*)d_in[2];
  const float* W1 = (const float*)d_in[3];
  const float* b1 = (const float*)d_in[4];
  const float* W2 = (const float*)d_in[5];
  const float* b2 = (const float*)d_in[6];
  float* out = (float*)d_out;
  char* ws = (char*)d_ws;
  if (ws_size < WS_BASE) return;
  bool use_ybuf = ws_size >= WS_FULL;

  int*   counts = (int*)(ws + O_COUNTS);
  int*   base   = (int*)(ws + O_BASE);
  int*   tokb   = (int*)(ws + O_TOKB);
  float* tokw   = (float*)(ws + O_TOKW);
  int*   ce     = (int*)(ws + O_CE);
  int*   cp     = (int*)(ws + O_CP);
  float* cw     = (float*)(ws + O_CW);
  __hip_bfloat16* zbf  = (__hip_bfloat16*)(ws + O_ZBF);
  __hip_bfloat16* w1t  = (__hip_bfloat16*)(ws + O_W1T);
  __hip_bfloat16* w2t  = (__hip_bfloat16*)(ws + O_W2T);
  __hip_bfloat16* hbuf = (__hip_bfloat16*)(ws + O_HBUF);
  float* ybuf = use_ybuf ? (float*)(ws + O_YBUF) : nullptr;

  k_zcnt<<<1, 64, 0, stream>>>(counts);
  if (!use_ybuf) k_zout<<<512, 256, 0, stream>>>(out);
  k_transpose<<<dim3(NHID / 32, DIM / 32, NEXP), 256, 0, stream>>>(W1, w1t, DIM, NHID);
  k_transpose<<<dim3(DIM / 32, NHID / 32, NEXP), 256, 0, stream>>>(W2, w2t, NHID, DIM);
  k_gate<<<BTOK / GATE_TOK, 256, 0, stream>>>(z, Wg, bg, counts, tokb, tokw, ce, cp, cw, zbf);
  k_base<<<1, 64, 0, stream>>>(counts, base);
  for (int half = 0; half < 2; half++) {
    k_gemm1<<<dim3(16, HHALF / 128, NEXP), 256, 0, stream>>>(
        zbf, w1t, b1, counts, base, tokb, hbuf, half * HHALF);
    k_gemm2<<<dim3(16, DIM / 128, NEXP), 256, 0, stream>>>(
        hbuf, w2t, b2, counts, base, tokb, tokw, out, ybuf, half * HHALF, half);
  }
  if (use_ybuf)
    k_combine<<<BTOK, 256, 0, stream>>>(ybuf, base, ce, cp, cw, out);
}